// Round 5
// baseline (795.613 us; speedup 1.0000x reference)
//
#include <hip/hip_runtime.h>
#include <math.h>

#define NEG_SLOPE 0.1f

constexpr int Bn = 512;
constexpr int Sn = 256;
constexpr int Dn = 256;

typedef short bf16x8 __attribute__((ext_vector_type(8)));
typedef float f32x4 __attribute__((ext_vector_type(4)));

__device__ inline ushort f2bf(float f) { // round-to-nearest-even bf16 bits
  uint u = __float_as_uint(f);
  uint r = u + 0x7FFFu + ((u >> 16) & 1u);
  return (ushort)(r >> 16);
}

// Raw barrier: drains LDS ops but NOT vmcnt — global prefetches ride across.
#define BAR() asm volatile("s_waitcnt lgkmcnt(0)\n\ts_barrier" ::: "memory")

// ---------------------------------------------------------------------------
// Single fused kernel. One block per b, 1024 threads = 16 waves, 1 block/CU.
// Phase 0: per-block vlr (v_l, v_r, c_l, c_r) from w1/a_w/b1 (L2 reads).
// Phase A: Wh^T[b] (256x256 bf16, XOR-swizzled) in LDS. 4 groups x 4 waves,
//          A/B fragments built in registers from global fp32 x / w1 —
//          NO staging LDS, NO barriers. e_l/e_r exact fp32 dots -> LDS.
// Phase B: wave w owns output rows [w*16, w*16+16). Scores->exp packed
//          directly into the MFMA A-fragment in registers (lane(q,c) = row c,
//          cols q*8..+8). B from WhT LDS. NO barriers. Row-sum via 2 shuffles.
// Exactly ONE block-wide barrier (A->B) + 2 in phase 0.
// ---------------------------------------------------------------------------
__global__ __launch_bounds__(1024) void k_all(const float* __restrict__ x,
                                              const float* __restrict__ pos,
                                              const float* __restrict__ w1,
                                              const float* __restrict__ b1,
                                              const float* __restrict__ a_w,
                                              const float* __restrict__ a_b,
                                              float* __restrict__ out) {
  __shared__ __align__(16) ushort WhT_s[65536]; // 128 KB, swizzled ^((n&7)<<3)
  __shared__ __align__(16) float scr[2048];     // 8 KB phase-0 partials
  __shared__ __align__(16) float vl_s[256];
  __shared__ __align__(16) float vr_s[256];
  __shared__ __align__(16) float el_s[256];
  __shared__ __align__(16) float er_s[256];
  __shared__ float clp[8];

  const int t = threadIdx.x;
  const int wave = t >> 6, lane = t & 63;
  const int q = lane >> 4, c = lane & 15;
  const int b = blockIdx.x;

  // ---------------- Phase 0: per-block vlr ----------------
  {
    const int d = t & 255, seg = t >> 8;
    float vl = 0.f, vr = 0.f;
    const float* wp = w1 + (size_t)(seg * 64) * 256 + d;
    const float* awl = a_w + seg * 64;
    const float* awr = a_w + 256 + seg * 64;
#pragma unroll 8
    for (int e = 0; e < 64; ++e) {
      float w = wp[(size_t)e * 256];
      vl += w * awl[e];
      vr += w * awr[e];
    }
    scr[seg * 256 + d] = vl;
    scr[1024 + seg * 256 + d] = vr;
  }
  __syncthreads();
  if (t < 256) {
    vl_s[t] = scr[t] + scr[256 + t] + scr[512 + t] + scr[768 + t];
    vr_s[t] = scr[1024 + t] + scr[1280 + t] + scr[1536 + t] + scr[1792 + t];
    float pl = b1[t] * a_w[t], pr = b1[t] * a_w[256 + t];
#pragma unroll
    for (int o = 1; o < 64; o <<= 1) {
      pl += __shfl_xor(pl, o);
      pr += __shfl_xor(pr, o);
    }
    if (lane == 0) { clp[wave] = pl; clp[4 + wave] = pr; }
  }
  __syncthreads();
  const float cl = clp[0] + clp[1] + clp[2] + clp[3];
  const float cr = clp[4] + clp[5] + clp[6] + clp[7];
  const float ab = a_b[0];

  // ---------------- Phase A ----------------
  // group g = wave>>2 owns s-rows [g*64, g*64+64); wg = wave&3 -> n-slice.
  const int g = wave >> 2, wg = wave & 3;
  const int n0A = wg * 64;

  f32x4 acc[4][4];
#pragma unroll
  for (int mi = 0; mi < 4; ++mi)
#pragma unroll
    for (int nt = 0; nt < 4; ++nt) acc[mi][nt] = (f32x4){0.f, 0.f, 0.f, 0.f};
  float slm[4] = {0.f, 0.f, 0.f, 0.f}, srm[4] = {0.f, 0.f, 0.f, 0.f};
  float b1v[4];
#pragma unroll
  for (int nt = 0; nt < 4; ++nt) b1v[nt] = b1[n0A + nt * 16 + c];

  const float* xg = x + (size_t)b * 65536 + (size_t)(g * 64 + c) * 256 + q * 8;
  const float* w1g = w1 + (size_t)(n0A + c) * 256 + q * 8;

#pragma unroll
  for (int st = 0; st < 8; ++st) {
    const int k0 = st * 32;
    bf16x8 ah[4];
    {
      float4 vla = *(const float4*)&vl_s[k0 + q * 8];
      float4 vlb = *(const float4*)&vl_s[k0 + q * 8 + 4];
      float4 vra = *(const float4*)&vr_s[k0 + q * 8];
      float4 vrb = *(const float4*)&vr_s[k0 + q * 8 + 4];
#pragma unroll
      for (int mi = 0; mi < 4; ++mi) {
        const float* p = xg + mi * 16 * 256 + k0;
        float4 xa = *(const float4*)p;
        float4 xc = *(const float4*)(p + 4);
        slm[mi] += xa.x * vla.x + xa.y * vla.y + xa.z * vla.z + xa.w * vla.w +
                   xc.x * vlb.x + xc.y * vlb.y + xc.z * vlb.z + xc.w * vlb.w;
        srm[mi] += xa.x * vra.x + xa.y * vra.y + xa.z * vra.z + xa.w * vra.w +
                   xc.x * vrb.x + xc.y * vrb.y + xc.z * vrb.z + xc.w * vrb.w;
        union { bf16x8 v; ushort u[8]; } ua;
        ua.u[0] = f2bf(xa.x); ua.u[1] = f2bf(xa.y);
        ua.u[2] = f2bf(xa.z); ua.u[3] = f2bf(xa.w);
        ua.u[4] = f2bf(xc.x); ua.u[5] = f2bf(xc.y);
        ua.u[6] = f2bf(xc.z); ua.u[7] = f2bf(xc.w);
        ah[mi] = ua.v;
      }
    }
#pragma unroll
    for (int nt = 0; nt < 4; ++nt) {
      const float* p = w1g + nt * 16 * 256 + k0;
      float4 wa = *(const float4*)p;
      float4 wc = *(const float4*)(p + 4);
      union { bf16x8 v; ushort u[8]; } ub;
      ub.u[0] = f2bf(wa.x); ub.u[1] = f2bf(wa.y);
      ub.u[2] = f2bf(wa.z); ub.u[3] = f2bf(wa.w);
      ub.u[4] = f2bf(wc.x); ub.u[5] = f2bf(wc.y);
      ub.u[6] = f2bf(wc.z); ub.u[7] = f2bf(wc.w);
#pragma unroll
      for (int mi = 0; mi < 4; ++mi)
        acc[mi][nt] = __builtin_amdgcn_mfma_f32_16x16x32_bf16(ah[mi], ub.v, acc[mi][nt], 0, 0, 0);
    }
  }

  // e_l/e_r: exact fp32; lanes (q,c) hold k-slices of row g*64+mi*16+c
#pragma unroll
  for (int mi = 0; mi < 4; ++mi) {
    float s1 = slm[mi]; s1 += __shfl_xor(s1, 16); s1 += __shfl_xor(s1, 32);
    float s2 = srm[mi]; s2 += __shfl_xor(s2, 16); s2 += __shfl_xor(s2, 32);
    if (wg == 0 && q == 0) {
      el_s[g * 64 + mi * 16 + c] = s1 + cl;
      er_s[g * 64 + mi * 16 + c] = s2 + cr;
    }
  }

  // WhT store (+b1), swizzled: value at [n][s], n = col of Wh, s = row
#pragma unroll
  for (int mi = 0; mi < 4; ++mi)
#pragma unroll
    for (int nt = 0; nt < 4; ++nt) {
      ushort4 h;
      ushort* hp = (ushort*)&h;
#pragma unroll
      for (int reg = 0; reg < 4; ++reg) hp[reg] = f2bf(acc[mi][nt][reg] + b1v[nt]);
      uint idx = (uint)(n0A + nt * 16 + c) * 256 + (uint)(g * 64 + mi * 16 + q * 4);
      idx ^= (uint)((c & 7) << 3);
      *(ushort4*)&WhT_s[idx] = h;
    }

  // pos prefetch for phase-B chunks 0,1 (in flight across the barrier)
  const int rowbase = wave * 16;
  const float* posr = pos + ((size_t)b * 256 + rowbase + c) * 256 + q * 8;
  float4 P00 = *(const float4*)posr;
  float4 P01 = *(const float4*)(posr + 4);
  float4 P10 = *(const float4*)(posr + 32);
  float4 P11 = *(const float4*)(posr + 36);

  BAR(); // the ONE phase barrier: WhT_s, el_s, er_s complete

  // ---------------- Phase B ----------------
  const float el_c = el_s[rowbase + c];
  f32x4 aB[16];
#pragma unroll
  for (int nt = 0; nt < 16; ++nt) aB[nt] = (f32x4){0.f, 0.f, 0.f, 0.f};
  float psum = 0.f;

#pragma unroll
  for (int ch = 0; ch < 8; ++ch) {
    const int jk = ch * 32;
    float4 PN0, PN1;
    if (ch < 6) {
      PN0 = *(const float4*)(posr + jk + 64);
      PN1 = *(const float4*)(posr + jk + 68);
    }
    float4 er0 = *(const float4*)&er_s[jk + q * 8];
    float4 er1 = *(const float4*)&er_s[jk + q * 8 + 4];
    float ev[8];
    {
      float s;
      s = el_c + er0.x + ab; s = (s >= 0.f) ? s : NEG_SLOPE * s; s += P00.x; ev[0] = __expf(s);
      s = el_c + er0.y + ab; s = (s >= 0.f) ? s : NEG_SLOPE * s; s += P00.y; ev[1] = __expf(s);
      s = el_c + er0.z + ab; s = (s >= 0.f) ? s : NEG_SLOPE * s; s += P00.z; ev[2] = __expf(s);
      s = el_c + er0.w + ab; s = (s >= 0.f) ? s : NEG_SLOPE * s; s += P00.w; ev[3] = __expf(s);
      s = el_c + er1.x + ab; s = (s >= 0.f) ? s : NEG_SLOPE * s; s += P01.x; ev[4] = __expf(s);
      s = el_c + er1.y + ab; s = (s >= 0.f) ? s : NEG_SLOPE * s; s += P01.y; ev[5] = __expf(s);
      s = el_c + er1.z + ab; s = (s >= 0.f) ? s : NEG_SLOPE * s; s += P01.z; ev[6] = __expf(s);
      s = el_c + er1.w + ab; s = (s >= 0.f) ? s : NEG_SLOPE * s; s += P01.w; ev[7] = __expf(s);
    }
    psum += ev[0] + ev[1] + ev[2] + ev[3] + ev[4] + ev[5] + ev[6] + ev[7];
    union { bf16x8 v; ushort u[8]; } up;
    up.u[0] = f2bf(ev[0]); up.u[1] = f2bf(ev[1]);
    up.u[2] = f2bf(ev[2]); up.u[3] = f2bf(ev[3]);
    up.u[4] = f2bf(ev[4]); up.u[5] = f2bf(ev[5]);
    up.u[6] = f2bf(ev[6]); up.u[7] = f2bf(ev[7]);
#pragma unroll
    for (int nt = 0; nt < 16; ++nt) {
      uint idx = ((uint)(nt * 16 + c) * 256 + (uint)(jk + q * 8)) ^ (uint)((c & 7) << 3);
      bf16x8 bfr = *(const bf16x8*)&WhT_s[idx];
      aB[nt] = __builtin_amdgcn_mfma_f32_16x16x32_bf16(up.v, bfr, aB[nt], 0, 0, 0);
    }
    P00 = P10; P01 = P11; P10 = PN0; P11 = PN1;
  }

  // row-sum: lane (q,c) has partial for row c; reduce over the 4 q-lanes
  psum += __shfl_xor(psum, 16);
  psum += __shfl_xor(psum, 32);
  // C-frag rows are q*4+reg -> fetch that row's sum from lane (q*4+reg)
  float alpha[4];
#pragma unroll
  for (int reg = 0; reg < 4; ++reg) alpha[reg] = 1.0f / __shfl(psum, q * 4 + reg);

  float* outb = out + ((size_t)b * 256 + rowbase) * 256;
#pragma unroll
  for (int nt = 0; nt < 16; ++nt)
#pragma unroll
    for (int reg = 0; reg < 4; ++reg) {
      float v = aB[nt][reg] * alpha[reg];
      v = (v > 0.f) ? v : (__expf(v) - 1.0f);
      outb[(size_t)(q * 4 + reg) * 256 + nt * 16 + c] = v;
    }
}

// ---------------------------------------------------------------------------
extern "C" void kernel_launch(void* const* d_in, const int* in_sizes, int n_in,
                              void* d_out, int out_size, void* d_ws, size_t ws_size,
                              hipStream_t stream) {
  const float* x   = (const float*)d_in[0];
  const float* pos = (const float*)d_in[1];
  const float* w1  = (const float*)d_in[2];
  const float* b1  = (const float*)d_in[3];
  const float* a_w = (const float*)d_in[4];
  const float* a_b = (const float*)d_in[5];
  float* out = (float*)d_out;

  k_all<<<dim3(Bn), dim3(1024), 0, stream>>>(x, pos, w1, b1, a_w, a_b, out);
}